// Round 7
// baseline (1356.563 us; speedup 1.0000x reference)
//
#include <hip/hip_runtime.h>

typedef __attribute__((ext_vector_type(8))) short bf16x8;
typedef __attribute__((ext_vector_type(4))) float f32x4;

#define MFMA_B16(A,B,C) __builtin_amdgcn_mfma_f32_16x16x32_bf16((A),(B),(C),0,0,0)

// ---- fragment layout constants (units: fragments of 1KB = 64 lanes * 8 bf16) ----
#define FO_ENC1 0
#define FO_PRI1 48
#define FO_DEC1 88
#define FO_GIH  136
#define FO_GHH  184
#define FO_ENC2 280
#define FO_PRI2 312
#define FO_DEC2 344
#define FO_MS   376
#define FO_DECMS 408
#define NFRAG   412

#define MS 200
#define TS 136

__device__ __forceinline__ unsigned short f2bf(float f) {
  union { float f; unsigned u; } v; v.f = f;
  unsigned r = (v.u + 0x7fffu + ((v.u >> 16) & 1u)) >> 16;
  return (unsigned short)r;
}
__device__ __forceinline__ float bf2f(unsigned short h) {
  union { unsigned u; float f; } v; v.u = ((unsigned)h) << 16;
  return v.f;
}
__device__ __forceinline__ float sigm_(float x) { return 1.f / (1.f + __expf(-x)); }
__device__ __forceinline__ float tanh_(float x) {
  x = fminf(fmaxf(x, -15.f), 15.f);
  float e = __expf(-2.f * x);
  return (1.f - e) / (1.f + e);
}
__device__ __forceinline__ float splus_(float x) {
  return fmaxf(x, 0.f) + log1pf(__expf(-fabsf(x)));
}
// async global->LDS DMA: no VGPR round-trip; LDS dest = wave-uniform base + lane*size
__device__ __forceinline__ void dma16(const void* g, void* l) {
  __builtin_amdgcn_global_load_lds((const __attribute__((address_space(1))) void*)g,
                                   (__attribute__((address_space(3))) void*)l, 16, 0, 0);
}
__device__ __forceinline__ void dma4(const void* g, void* l) {
  __builtin_amdgcn_global_load_lds((const __attribute__((address_space(1))) void*)g,
                                   (__attribute__((address_space(3))) void*)l, 4, 0, 0);
}

// ============================ PREP KERNEL ============================
// Master activation k-layout: [x:0..1 | z:2..33 | y:34..43 | pad:44..63 | h:64..191]
// Fragment (64 lanes x 8 bf16): lane l, elem j -> B[mk = kb*32 + (l>>4)*8 + j][n = nt*16 + (l&15)]
__global__ void prep_kernel(const float* __restrict__ ew1, const float* __restrict__ pw1,
                            const float* __restrict__ dw1, const float* __restrict__ wih,
                            const float* __restrict__ whh, const float* __restrict__ ew2,
                            const float* __restrict__ pw2, const float* __restrict__ dw2,
                            const float* __restrict__ emw, const float* __restrict__ esw,
                            const float* __restrict__ pmw, const float* __restrict__ psw,
                            const float* __restrict__ dmw, const float* __restrict__ dsw,
                            unsigned short* __restrict__ ws)
{
  int blk = blockIdx.x;
  int a = blk / NFRAG, f = blk % NFRAG;
  int l = threadIdx.x, lg = l >> 4, ln = l & 15;
  float v[8];

  if (f < FO_PRI1) {                       // enc1
    int fi = f, nt = fi / 6, kb = fi % 6, n = nt * 16 + ln;
#pragma unroll
    for (int j = 0; j < 8; ++j) {
      int mk = kb * 32 + lg * 8 + j;
      int r = (mk < 2) ? mk : (mk >= 34 && mk < 44) ? 2 + (mk - 34)
            : (mk >= 64) ? 12 + (mk - 64) : -1;
      v[j] = (r >= 0) ? ew1[((size_t)a * 140 + r) * 128 + n] : 0.f;
    }
  } else if (f < FO_DEC1) {                // pri1
    int fi = f - FO_PRI1, nt = fi / 5, kb = 1 + fi % 5, n = nt * 16 + ln;
#pragma unroll
    for (int j = 0; j < 8; ++j) {
      int mk = kb * 32 + lg * 8 + j;
      int r = (mk >= 34 && mk < 44) ? (mk - 34) : (mk >= 64) ? 10 + (mk - 64) : -1;
      v[j] = (r >= 0) ? pw1[((size_t)a * 138 + r) * 128 + n] : 0.f;
    }
  } else if (f < FO_GIH) {                 // dec1
    int fi = f - FO_DEC1, nt = fi / 6, kb = fi % 6, n = nt * 16 + ln;
#pragma unroll
    for (int j = 0; j < 8; ++j) {
      int mk = kb * 32 + lg * 8 + j;
      int r = (mk >= 2 && mk < 34) ? 10 + (mk - 2) : (mk >= 34 && mk < 44) ? (mk - 34)
            : (mk >= 64) ? 42 + (mk - 64) : -1;
      v[j] = (r >= 0) ? dw1[((size_t)a * 170 + r) * 128 + n] : 0.f;
    }
  } else if (f < FO_GHH) {                 // gru_ih
    int fi = f - FO_GIH, nt = fi / 2, kb = fi % 2, n = nt * 16 + ln;
#pragma unroll
    for (int j = 0; j < 8; ++j) {
      int mk = kb * 32 + lg * 8 + j;
      v[j] = (mk < 34) ? wih[((size_t)a * 34 + mk) * 384 + n] : 0.f;
    }
  } else if (f < FO_ENC2) {                // gru_hh
    int fi = f - FO_GHH, nt = fi / 4, kb = fi % 4, n = nt * 16 + ln;
#pragma unroll
    for (int j = 0; j < 8; ++j) {
      int r = kb * 32 + lg * 8 + j;
      v[j] = whh[((size_t)a * 128 + r) * 384 + n];
    }
  } else if (f < FO_DEC2) {                // enc2 / pri2
    int fi = f - FO_ENC2;
    const float* W = (fi < 32) ? ew2 : pw2;
    fi &= 31;
    int nt = fi / 4, kb = fi % 4, n = nt * 16 + ln;
#pragma unroll
    for (int j = 0; j < 8; ++j) {
      int r = kb * 32 + lg * 8 + j;
      v[j] = W[((size_t)a * 128 + r) * 128 + n];
    }
  } else if (f < FO_MS) {                  // dec2
    int fi = f - FO_DEC2, nt = fi / 4, kb = fi % 4, n = nt * 16 + ln;
#pragma unroll
    for (int j = 0; j < 8; ++j) {
      int r = kb * 32 + lg * 8 + j;
      v[j] = dw2[((size_t)a * 128 + r) * 128 + n];
    }
  } else if (f < FO_DECMS) {               // enc_m / enc_s / pri_m / pri_s
    int fi = f - FO_MS, mat = fi / 8, rem = fi % 8, nt = rem / 4, kb = rem % 4;
    int n = nt * 16 + ln;
    const float* W = (mat == 0) ? emw : (mat == 1) ? esw : (mat == 2) ? pmw : psw;
#pragma unroll
    for (int j = 0; j < 8; ++j) {
      int r = kb * 32 + lg * 8 + j;
      v[j] = W[((size_t)a * 128 + r) * 32 + n];
    }
  } else {                                 // dec m/s packed
    int kb = f - FO_DECMS;
#pragma unroll
    for (int j = 0; j < 8; ++j) {
      int r = kb * 32 + lg * 8 + j;
      v[j] = (ln < 2) ? dmw[((size_t)a * 128 + r) * 2 + ln]
           : (ln < 4) ? dsw[((size_t)a * 128 + r) * 2 + (ln - 2)] : 0.f;
    }
  }
  unsigned short* dst = ws + (size_t)blk * 512 + l * 8;
#pragma unroll
  for (int j = 0; j < 8; ++j) dst[j] = f2bf(v[j]);
}

// ============================ MAIN KERNEL ============================
// grid (32,5), 512 thr = 8 waves. 11 jobs/step, weights DMA-staged (global_load_lds)
// into double-buffered 48KB LDS one job ahead; __syncthreads' vmcnt(0) drain at each
// job boundary is the completion wait. eps/states HBM streams also DMA-staged ahead.
// Jobs: 1 enc1(+prev dec-head/NLL, HBM prefetch) | 2 pri1 | 3 enc2 | 4 pri2 | 5 heads
//  | 6 ghh_r + z/KL | 7 ghh_z | 8 ghh_n | 9 dec1 | 10 gih+GRU | 11 dec2 + y/x->master
__global__ __launch_bounds__(512, 1) void vrnn_main(
    const float* __restrict__ states, const float* __restrict__ eps,
    const float* __restrict__ eb1, const float* __restrict__ eb2,
    const float* __restrict__ emb, const float* __restrict__ esb,
    const float* __restrict__ pb1, const float* __restrict__ pb2,
    const float* __restrict__ pmb, const float* __restrict__ psb,
    const float* __restrict__ db1, const float* __restrict__ db2,
    const float* __restrict__ dmb, const float* __restrict__ dsb,
    const float* __restrict__ bih, const float* __restrict__ bhh,
    const unsigned short* __restrict__ frags, float* __restrict__ out)
{
  const int a = blockIdx.y;
  const int b0 = blockIdx.x * 16;
  const int tid = threadIdx.x;
  const int w = tid >> 6, l = tid & 63, lg = l >> 4, ln = l & 15;

  __shared__ __align__(16) unsigned short wstage[2][48 * 512];
  __shared__ __align__(16) unsigned short dms_lds[4 * 512];
  __shared__ __align__(16) unsigned short master[16 * MS];
  __shared__ __align__(16) unsigned short t1e[16 * TS], t1p[16 * TS];
  __shared__ __align__(16) unsigned short he[16 * TS], hp[16 * TS];
  __shared__ float msbuf[4][16][32];
  __shared__ float epsb[2][512];
  __shared__ float yb[2][192];
  __shared__ float xb[64];
  __shared__ float red[16];

  const unsigned short* fa = frags + (size_t)a * NFRAG * 512;

  // ---- one-time: pin dms, zero master
  {
    const uint4* s3 = (const uint4*)(fa + (size_t)FO_DECMS * 512);
    uint4* d3 = (uint4*)dms_lds;
    if (tid < 256) d3[tid] = s3[tid];
  }
  for (int i = tid; i < 16 * MS; i += 512) master[i] = 0;

  // ---- biases (small register set)
  float eb1v = eb1[a * 128 + w * 16 + ln], pb1v = pb1[a * 128 + w * 16 + ln];
  float eb2v = eb2[a * 128 + w * 16 + ln], pb2v = pb2[a * 128 + w * 16 + ln];
  float db2v = db2[a * 128 + w * 16 + ln], d1b = db1[a * 128 + w * 16 + ln];
  float ghbv[3], gibv[3];
#pragma unroll
  for (int g = 0; g < 3; ++g) {
    ghbv[g] = bhh[a * 384 + g * 128 + w * 16 + ln];
    gibv[g] = bih[a * 384 + g * 128 + w * 16 + ln];
  }
  const int hmat = w >> 1, hnt = w & 1;
  const float* hb_ = (hmat == 0) ? emb : (hmat == 1) ? esb : (hmat == 2) ? pmb : psb;
  float hbv = hb_[a * 32 + hnt * 16 + ln];
  float dmsb = (w == 0) ? ((ln < 2) ? dmb[a * 2 + ln] : (ln < 4) ? dsb[a * 2 + (ln - 2)] : 0.f) : 0.f;

  __syncthreads();

  // ---- prologue staging: y(0)/x(0) direct; eps(0) + enc1 via DMA
  if (tid < 160) {
    int r = tid / 10, c = tid - r * 10;
    master[r * MS + 34 + c] = f2bf(states[(size_t)b0 * 10 + tid]);
  }
  if (tid >= 192 && tid < 224) {
    int i = tid - 192, r = i >> 1, c = i & 1;
    master[r * MS + c] = f2bf(states[((size_t)512 + b0 + r) * 10 + a * 2 + c]);
  }
#pragma unroll
  for (int kb = 0; kb < 6; ++kb)
    dma16(fa + (size_t)(FO_ENC1 + w * 6 + kb) * 512 + l * 8, &wstage[0][(w * 6 + kb) * 512]);
  dma4(eps + (((size_t)(b0 + 2 * w + (l >> 5))) * 5 + a) * 32 + (l & 31), &epsb[0][w * 64]);

  float kl = 0.f, nll = 0.f;
  f32x4 ghr, ghz, ghn;
  __syncthreads();

  for (int t = 0; t < 127; ++t) {
    unsigned short* const B0 = wstage[t & 1];
    unsigned short* const B1 = wstage[(t + 1) & 1];

    // ===== J1: enc1 [B0]; stage pri1->B1; HBM prefetch; w0: prev dec-head+NLL =====
    {
#pragma unroll
      for (int kb = 0; kb < 5; ++kb)
        dma16(fa + (size_t)(FO_PRI1 + w * 5 + kb) * 512 + l * 8, &B1[(w * 5 + kb) * 512]);
      if (t < 126)
        dma4(eps + (((size_t)(t + 1) * 512 + b0 + 2 * w + (l >> 5)) * 5 + a) * 32 + (l & 31),
             &epsb[(t + 1) & 1][w * 64]);
      if (w >= 1 && w <= 3) {
        int idx = (w - 1) * 64 + l;
        int f = (idx < 160) ? idx : 0;
        dma4(states + ((size_t)(t + 1) * 512 + b0) * 10 + f, &yb[t & 1][(w - 1) * 64]);
      }
      if (w == 4 && t < 126) {
        int rr = (l < 32) ? l : 0;
        dma4(states + ((size_t)(t + 2) * 512 + b0 + (rr >> 1)) * 10 + a * 2 + (rr & 1), xb);
      }
      if (w == 0 && t > 0) {
        f32x4 acc = {dmsb, dmsb, dmsb, dmsb};
#pragma unroll
        for (int kb = 0; kb < 4; ++kb) {
          bf16x8 ad = *(const bf16x8*)&he[ln * TS + kb * 32 + lg * 8];
          bf16x8 bf = *(const bf16x8*)&dms_lds[kb * 512 + l * 8];
          acc = MFMA_B16(ad, bf, acc);
        }
#pragma unroll
        for (int q = 0; q < 4; ++q) {
          float sv = __shfl(splus_(acc[q]), l + 2);
          if (ln < 2) {
            float xvv = yb[(t ^ 1) & 1][(4 * lg + q) * 10 + a * 2 + ln];
            float d = (xvv - acc[q]) / sv;
            nll += 0.9189385332f + __logf(sv) + 0.5f * d * d;
          }
        }
      }
      bf16x8 am[6];
#pragma unroll
      for (int kb = 0; kb < 6; ++kb)
        am[kb] = *(const bf16x8*)&master[ln * MS + kb * 32 + lg * 8];
      f32x4 a1 = {eb1v, eb1v, eb1v, eb1v};
#pragma unroll
      for (int kb = 0; kb < 6; ++kb)
        a1 = MFMA_B16(am[kb], *(const bf16x8*)&B0[(w * 6 + kb) * 512 + l * 8], a1);
#pragma unroll
      for (int q = 0; q < 4; ++q)
        t1e[(4 * lg + q) * TS + w * 16 + ln] = f2bf(fmaxf(a1[q], 0.f));
    }
    __syncthreads();

    // ===== J2: pri1 [B1]; stage enc2->B0 =====
    {
#pragma unroll
      for (int kb = 0; kb < 4; ++kb)
        dma16(fa + (size_t)(FO_ENC2 + w * 4 + kb) * 512 + l * 8, &B0[(w * 4 + kb) * 512]);
      bf16x8 am[5];
#pragma unroll
      for (int kb = 0; kb < 5; ++kb)
        am[kb] = *(const bf16x8*)&master[ln * MS + (kb + 1) * 32 + lg * 8];
      f32x4 a2 = {pb1v, pb1v, pb1v, pb1v};
#pragma unroll
      for (int kb = 0; kb < 5; ++kb)
        a2 = MFMA_B16(am[kb], *(const bf16x8*)&B1[(w * 5 + kb) * 512 + l * 8], a2);
#pragma unroll
      for (int q = 0; q < 4; ++q)
        t1p[(4 * lg + q) * TS + w * 16 + ln] = f2bf(fmaxf(a2[q], 0.f));
    }
    __syncthreads();

    // ===== J3: enc2 [B0] -> he; stage pri2->B1 =====
    {
#pragma unroll
      for (int kb = 0; kb < 4; ++kb)
        dma16(fa + (size_t)(FO_PRI2 + w * 4 + kb) * 512 + l * 8, &B1[(w * 4 + kb) * 512]);
      bf16x8 ae[4];
#pragma unroll
      for (int kb = 0; kb < 4; ++kb)
        ae[kb] = *(const bf16x8*)&t1e[ln * TS + kb * 32 + lg * 8];
      f32x4 a1 = {eb2v, eb2v, eb2v, eb2v};
#pragma unroll
      for (int kb = 0; kb < 4; ++kb)
        a1 = MFMA_B16(ae[kb], *(const bf16x8*)&B0[(w * 4 + kb) * 512 + l * 8], a1);
#pragma unroll
      for (int q = 0; q < 4; ++q)
        he[(4 * lg + q) * TS + w * 16 + ln] = f2bf(fmaxf(a1[q], 0.f));
    }
    __syncthreads();

    // ===== J4: pri2 [B1] -> hp; stage ms->B0 =====
    {
#pragma unroll
      for (int kb = 0; kb < 4; ++kb)
        dma16(fa + (size_t)(FO_MS + w * 4 + kb) * 512 + l * 8, &B0[(w * 4 + kb) * 512]);
      bf16x8 ap[4];
#pragma unroll
      for (int kb = 0; kb < 4; ++kb)
        ap[kb] = *(const bf16x8*)&t1p[ln * TS + kb * 32 + lg * 8];
      f32x4 a2 = {pb2v, pb2v, pb2v, pb2v};
#pragma unroll
      for (int kb = 0; kb < 4; ++kb)
        a2 = MFMA_B16(ap[kb], *(const bf16x8*)&B1[(w * 4 + kb) * 512 + l * 8], a2);
#pragma unroll
      for (int q = 0; q < 4; ++q)
        hp[(4 * lg + q) * TS + w * 16 + ln] = f2bf(fmaxf(a2[q], 0.f));
    }
    __syncthreads();

    // ===== J5: heads [B0] -> msbuf (wave w: matrix w>>1, n-tile w&1); stage ghh_r->B1 =====
    {
#pragma unroll
      for (int kb = 0; kb < 4; ++kb)
        dma16(fa + (size_t)(FO_GHH + w * 4 + kb) * 512 + l * 8, &B1[(w * 4 + kb) * 512]);
      const unsigned short* hs = (hmat < 2) ? he : hp;
      bf16x8 ah[4];
#pragma unroll
      for (int kb = 0; kb < 4; ++kb)
        ah[kb] = *(const bf16x8*)&hs[ln * TS + kb * 32 + lg * 8];
      f32x4 acc = {hbv, hbv, hbv, hbv};
#pragma unroll
      for (int kb = 0; kb < 4; ++kb)
        acc = MFMA_B16(ah[kb], *(const bf16x8*)&B0[(w * 4 + kb) * 512 + l * 8], acc);
#pragma unroll
      for (int q = 0; q < 4; ++q) {
        float vv = acc[q];
        if (hmat & 1) vv = splus_(vv);
        msbuf[hmat][4 * lg + q][hnt * 16 + ln] = vv;
      }
    }
    __syncthreads();

    // ===== J6: ghh_r [B1] -> ghr; z + KL (all 512 threads); stage ghh_z->B0 =====
    {
#pragma unroll
      for (int kb = 0; kb < 4; ++kb)
        dma16(fa + (size_t)(FO_GHH + 32 + w * 4 + kb) * 512 + l * 8, &B0[(w * 4 + kb) * 512]);
      bf16x8 ah[4];
#pragma unroll
      for (int kb = 0; kb < 4; ++kb)
        ah[kb] = *(const bf16x8*)&master[ln * MS + (kb + 2) * 32 + lg * 8];
      ghr = (f32x4){ghbv[0], ghbv[0], ghbv[0], ghbv[0]};
#pragma unroll
      for (int kb = 0; kb < 4; ++kb)
        ghr = MFMA_B16(ah[kb], *(const bf16x8*)&B1[(w * 4 + kb) * 512 + l * 8], ghr);
      int row = tid >> 5, zc = tid & 31;
      float em_ = msbuf[0][row][zc], es_ = msbuf[1][row][zc];
      float pm_ = msbuf[2][row][zc], ps_ = msbuf[3][row][zc];
      float e = epsb[t & 1][tid];
      master[row * MS + 2 + zc] = f2bf(em_ + es_ * e);
      float dm = em_ - pm_;
      kl += 0.5f * (2.f * __logf(ps_) - 2.f * __logf(es_) + (es_ * es_ + dm * dm) / (ps_ * ps_) - 1.f);
    }
    __syncthreads();

    // ===== J7: ghh_z [B0] -> ghz; stage ghh_n->B1 =====
    {
#pragma unroll
      for (int kb = 0; kb < 4; ++kb)
        dma16(fa + (size_t)(FO_GHH + 64 + w * 4 + kb) * 512 + l * 8, &B1[(w * 4 + kb) * 512]);
      bf16x8 ah[4];
#pragma unroll
      for (int kb = 0; kb < 4; ++kb)
        ah[kb] = *(const bf16x8*)&master[ln * MS + (kb + 2) * 32 + lg * 8];
      ghz = (f32x4){ghbv[1], ghbv[1], ghbv[1], ghbv[1]};
#pragma unroll
      for (int kb = 0; kb < 4; ++kb)
        ghz = MFMA_B16(ah[kb], *(const bf16x8*)&B0[(w * 4 + kb) * 512 + l * 8], ghz);
    }
    __syncthreads();

    // ===== J8: ghh_n [B1] -> ghn; stage dec1->B0 =====
    {
#pragma unroll
      for (int kb = 0; kb < 6; ++kb)
        dma16(fa + (size_t)(FO_DEC1 + w * 6 + kb) * 512 + l * 8, &B0[(w * 6 + kb) * 512]);
      bf16x8 ah[4];
#pragma unroll
      for (int kb = 0; kb < 4; ++kb)
        ah[kb] = *(const bf16x8*)&master[ln * MS + (kb + 2) * 32 + lg * 8];
      ghn = (f32x4){ghbv[2], ghbv[2], ghbv[2], ghbv[2]};
#pragma unroll
      for (int kb = 0; kb < 4; ++kb)
        ghn = MFMA_B16(ah[kb], *(const bf16x8*)&B1[(w * 4 + kb) * 512 + l * 8], ghn);
    }
    __syncthreads();

    // ===== J9: dec1 [B0] -> t1e; stage gih->B1 =====
    {
#pragma unroll
      for (int kb = 0; kb < 6; ++kb)
        dma16(fa + (size_t)(FO_GIH + w * 6 + kb) * 512 + l * 8, &B1[(w * 6 + kb) * 512]);
      bf16x8 am[6];
#pragma unroll
      for (int kb = 0; kb < 6; ++kb)
        am[kb] = *(const bf16x8*)&master[ln * MS + kb * 32 + lg * 8];
      f32x4 acc = {d1b, d1b, d1b, d1b};
#pragma unroll
      for (int kb = 0; kb < 6; ++kb)
        acc = MFMA_B16(am[kb], *(const bf16x8*)&B0[(w * 6 + kb) * 512 + l * 8], acc);
#pragma unroll
      for (int q = 0; q < 4; ++q)
        t1e[(4 * lg + q) * TS + w * 16 + ln] = f2bf(fmaxf(acc[q], 0.f));
    }
    __syncthreads();

    // ===== J10: gih [B1] + GRU elementwise (h cols w*16..+15); stage dec2->B0 =====
    {
#pragma unroll
      for (int kb = 0; kb < 4; ++kb)
        dma16(fa + (size_t)(FO_DEC2 + w * 4 + kb) * 512 + l * 8, &B0[(w * 4 + kb) * 512]);
      bf16x8 am2[2];
#pragma unroll
      for (int kb = 0; kb < 2; ++kb)
        am2[kb] = *(const bf16x8*)&master[ln * MS + kb * 32 + lg * 8];
      f32x4 gi[3];
#pragma unroll
      for (int g = 0; g < 3; ++g) {
        gi[g] = (f32x4){gibv[g], gibv[g], gibv[g], gibv[g]};
#pragma unroll
        for (int kb = 0; kb < 2; ++kb)
          gi[g] = MFMA_B16(am2[kb],
                           *(const bf16x8*)&B1[(g * 16 + w * 2 + kb) * 512 + l * 8], gi[g]);
      }
#pragma unroll
      for (int q = 0; q < 4; ++q) {
        float r_ = sigm_(gi[0][q] + ghr[q]);
        float u_ = sigm_(gi[1][q] + ghz[q]);
        float n_ = tanh_(gi[2][q] + r_ * ghn[q]);
        int off = (4 * lg + q) * MS + 64 + w * 16 + ln;
        float ho = bf2f(master[off]);
        master[off] = f2bf((1.f - u_) * n_ + u_ * ho);
      }
    }
    __syncthreads();

    // ===== J11: dec2 [B0] -> he(hd); y/x -> master; stage enc1(next)->B1 =====
    {
      if (t < 126) {
#pragma unroll
        for (int kb = 0; kb < 6; ++kb)
          dma16(fa + (size_t)(FO_ENC1 + w * 6 + kb) * 512 + l * 8, &B1[(w * 6 + kb) * 512]);
      }
      bf16x8 ad[4];
#pragma unroll
      for (int kb = 0; kb < 4; ++kb)
        ad[kb] = *(const bf16x8*)&t1e[ln * TS + kb * 32 + lg * 8];
      f32x4 acc = {db2v, db2v, db2v, db2v};
#pragma unroll
      for (int kb = 0; kb < 4; ++kb)
        acc = MFMA_B16(ad[kb], *(const bf16x8*)&B0[(w * 4 + kb) * 512 + l * 8], acc);
#pragma unroll
      for (int q = 0; q < 4; ++q)
        he[(4 * lg + q) * TS + w * 16 + ln] = f2bf(fmaxf(acc[q], 0.f));
      if (t < 126) {
        if (w >= 1 && w <= 3) {
          int i = (w - 1) * 64 + l;
          if (i < 160) {
            int r = i / 10, c = i - r * 10;
            master[r * MS + 34 + c] = f2bf(yb[t & 1][i]);
          }
        }
        if (w == 0 && l < 32)
          master[(l >> 1) * MS + (l & 1)] = f2bf(xb[l]);
      }
    }
    __syncthreads();
  }

  // ---- epilogue: dec-head + NLL for t=126 (w0); x(126)=states[127]=yb[0]
  if (w == 0) {
    f32x4 acc = {dmsb, dmsb, dmsb, dmsb};
#pragma unroll
    for (int kb = 0; kb < 4; ++kb) {
      bf16x8 ad = *(const bf16x8*)&he[ln * TS + kb * 32 + lg * 8];
      bf16x8 bf = *(const bf16x8*)&dms_lds[kb * 512 + l * 8];
      acc = MFMA_B16(ad, bf, acc);
    }
#pragma unroll
    for (int q = 0; q < 4; ++q) {
      float sv = __shfl(splus_(acc[q]), l + 2);
      if (ln < 2) {
        float xvv = yb[0][(4 * lg + q) * 10 + a * 2 + ln];
        float d = (xvv - acc[q]) / sv;
        nll += 0.9189385332f + __logf(sv) + 0.5f * d * d;
      }
    }
  }

  // ---- final reduction
#pragma unroll
  for (int off = 32; off > 0; off >>= 1) {
    kl += __shfl_down(kl, off);
    nll += __shfl_down(nll, off);
  }
  if (l == 0) { red[w] = kl; red[8 + w] = nll; }
  __syncthreads();
  if (tid == 0) {
    float K = 0.f, N = 0.f;
#pragma unroll
    for (int i = 0; i < 8; ++i) { K += red[i]; N += red[8 + i]; }
    atomicAdd(out, K);
    atomicAdd(out + 1, N);
  }
}

extern "C" void kernel_launch(void* const* d_in, const int* in_sizes, int n_in,
                              void* d_out, int out_size, void* d_ws, size_t ws_size,
                              hipStream_t stream) {
  (void)in_sizes; (void)n_in; (void)out_size; (void)ws_size;
  const float* states = (const float*)d_in[0];
  const float* eps    = (const float*)d_in[1];
  const float* ew1 = (const float*)d_in[2];
  const float* eb1 = (const float*)d_in[3];
  const float* ew2 = (const float*)d_in[4];
  const float* eb2 = (const float*)d_in[5];
  const float* emw = (const float*)d_in[6];
  const float* emb = (const float*)d_in[7];
  const float* esw = (const float*)d_in[8];
  const float* esb = (const float*)d_in[9];
  const float* pw1 = (const float*)d_in[10];
  const float* pb1 = (const float*)d_in[11];
  const float* pw2 = (const float*)d_in[12];
  const float* pb2 = (const float*)d_in[13];
  const float* pmw = (const float*)d_in[14];
  const float* pmb = (const float*)d_in[15];
  const float* psw = (const float*)d_in[16];
  const float* psb = (const float*)d_in[17];
  const float* dw1 = (const float*)d_in[18];
  const float* db1 = (const float*)d_in[19];
  const float* dw2 = (const float*)d_in[20];
  const float* db2 = (const float*)d_in[21];
  const float* dmw = (const float*)d_in[22];
  const float* dmb = (const float*)d_in[23];
  const float* dsw = (const float*)d_in[24];
  const float* dsb = (const float*)d_in[25];
  const float* wih = (const float*)d_in[26];
  const float* whh = (const float*)d_in[27];
  const float* bih = (const float*)d_in[28];
  const float* bhh = (const float*)d_in[29];

  unsigned short* frags = (unsigned short*)d_ws;
  float* out = (float*)d_out;

  hipMemsetAsync(d_out, 0, 2 * sizeof(float), stream);
  prep_kernel<<<dim3(5 * NFRAG), dim3(64), 0, stream>>>(
      ew1, pw1, dw1, wih, whh, ew2, pw2, dw2, emw, esw, pmw, psw, dmw, dsw, frags);
  vrnn_main<<<dim3(32, 5), dim3(512), 0, stream>>>(
      states, eps, eb1, eb2, emb, esb, pb1, pb2, pmb, psb,
      db1, db2, dmb, dsb, bih, bhh, frags, out);
}